// Round 2
// baseline (111.989 us; speedup 1.0000x reference)
//
#include <hip/hip_runtime.h>
#include <hip/hip_bf16.h>

#define B_N  4096
#define K_D  1024
#define BM   256
#define BK   64
#define KT   (K_D / BK)   // 16 K-tiles

typedef __bf16 bf16x8 __attribute__((ext_vector_type(8)));
typedef float  f32x4  __attribute__((ext_vector_type(4)));

// round-to-nearest-even float -> bf16 bits (inputs are finite normals; no NaN path needed)
__device__ __forceinline__ unsigned short f2bf(float x) {
    union { float f; unsigned int u; } v; v.f = x;
    unsigned int r = v.u + 0x7fffu + ((v.u >> 16) & 1u);
    return (unsigned short)(r >> 16);
}

// One block (256 threads) per row: compute L2 norm, write bf16 normalized row.
// Also zeroes rowsum[row] (and possum) so no separate memset node is needed.
__global__ void normalize_bf16(const float* __restrict__ f, unsigned short* __restrict__ fnb,
                               float* __restrict__ rowsum) {
    const int row = blockIdx.x;
    const int tid = threadIdx.x;
    float4 v = ((const float4*)(f + (size_t)row * K_D))[tid];
    float s = v.x * v.x + v.y * v.y + v.z * v.z + v.w * v.w;
#pragma unroll
    for (int m = 1; m < 64; m <<= 1) s += __shfl_xor(s, m, 64);
    __shared__ float wsum[4];
    if ((tid & 63) == 0) wsum[tid >> 6] = s;
    __syncthreads();
    float tot = wsum[0] + wsum[1] + wsum[2] + wsum[3];
    float scale = 1.0f / fmaxf(sqrtf(tot), 1e-12f);
    ushort4 o;
    o.x = f2bf(v.x * scale); o.y = f2bf(v.y * scale);
    o.z = f2bf(v.z * scale); o.w = f2bf(v.w * scale);
    ((ushort4*)(fnb + (size_t)row * K_D))[tid] = o;
    if (tid == 0) rowsum[row] = 0.0f;
    if (row == 0 && tid == 1) rowsum[B_N] = 0.0f;   // possum slot
}

// LDS tile layout: [row][8 slots of 16B], slot XOR-swizzled by (row&7) (T2).
// Stored via pre-swizzled GLOBAL source (global_load_lds writes linearly);
// read with the same XOR -> ds_read_b128 spreads 16 lanes over 8 bank groups.
__device__ __forceinline__ const bf16x8* lds_frag(const unsigned short* base, int row, int ks) {
    return (const bf16x8*)((const char*)base + row * (BK * 2) + (((ks ^ row) & 7) << 4));
}

// 256x256 tile of sim = fn*fn^T per block (full 16x16 grid = 1 block/CU).
// 8 waves (2M x 4N), per-wave 128x64 output = 8x4 fragments of 16x16x32 bf16 MFMA.
// K-loop: double-buffered LDS, counted vmcnt(8) (T4) with raw s_barrier -- tile t+2's
// loads stay in flight across the whole compute of tile t+1; never drain to 0 mid-loop.
// Epilogue: e = exp(10*dot) (0 on diag); rowsum via 16-lane butterflies + atomics;
// possum via wave+block reduction + 1 atomic per block.
__global__ __launch_bounds__(512, 2)
void gemm_exp_reduce(const unsigned short* __restrict__ fnb,
                     const int* __restrict__ labels,
                     float* __restrict__ rowsum,
                     float* __restrict__ possum) {
    __shared__ __align__(16) unsigned short AsB[2][BM * BK]; // 2 x 32 KB
    __shared__ __align__(16) unsigned short BsB[2][BM * BK]; // 2 x 32 KB
    __shared__ int   rlab[BM];
    __shared__ int   clab[BM];
    __shared__ float posred[8];

    const int bi = blockIdx.y, bj = blockIdx.x;
    const int row0 = bi * BM, col0 = bj * BM;
    const int tid  = threadIdx.x;
    const int lane = tid & 63, wave = tid >> 6;
    const int wr = wave >> 2, wc = wave & 3;          // 2M x 4N wave grid
    const int quad = lane >> 4, l15 = lane & 15;

    if (tid < BM) rlab[tid] = labels[row0 + tid];
    else          clab[tid - BM] = labels[col0 + tid - BM];

    f32x4 acc[8][4];
#pragma unroll
    for (int i = 0; i < 8; ++i)
#pragma unroll
        for (int j = 0; j < 4; ++j) {
            f32x4 z = {0.f, 0.f, 0.f, 0.f};
            acc[i][j] = z;
        }

    // Stage one K-tile (A rows row0..+255, B rows col0..+255, cols k0..k0+63).
    // Chunk c = ld*512+tid -> LDS bytes [c*16, +16) (linear, lane-ordered, as
    // global_load_lds requires); global source column pre-swizzled: slot^(row&7).
    auto stage = [&](int buf, int k0) {
#pragma unroll
        for (int ld = 0; ld < 4; ++ld) {
            int c  = ld * 512 + tid;
            int r  = c >> 3;
            int gc = ((c ^ r) & 7) << 3;
            __builtin_amdgcn_global_load_lds(
                (const unsigned int*)(fnb + (size_t)(row0 + r) * K_D + k0 + gc),
                (unsigned int*)&AsB[buf][c * 8], 16, 0, 0);
        }
#pragma unroll
        for (int ld = 0; ld < 4; ++ld) {
            int c  = ld * 512 + tid;
            int r  = c >> 3;
            int gc = ((c ^ r) & 7) << 3;
            __builtin_amdgcn_global_load_lds(
                (const unsigned int*)(fnb + (size_t)(col0 + r) * K_D + k0 + gc),
                (unsigned int*)&BsB[buf][c * 8], 16, 0, 0);
        }
    };

    // Prologue: tiles 0 and 1 in flight; wait only for tile 0 (vmcnt(8)).
    stage(0, 0);
    stage(1, BK);
    asm volatile("s_waitcnt vmcnt(8)" ::: "memory");
    __builtin_amdgcn_sched_barrier(0);
    __builtin_amdgcn_s_barrier();          // all waves' tile-0 chunks arrived
    __builtin_amdgcn_sched_barrier(0);

    for (int t = 0; t < KT; ++t) {
        const unsigned short* A  = AsB[t & 1];
        const unsigned short* Bb = BsB[t & 1];

        // B fragments for all 4 col-frags up front (8 ds_read_b128), A per 64-row half.
        bf16x8 bq[4][2];
#pragma unroll
        for (int fc = 0; fc < 4; ++fc)
#pragma unroll
            for (int kk = 0; kk < 2; ++kk)
                bq[fc][kk] = *lds_frag(Bb, wc * 64 + fc * 16 + l15, kk * 4 + quad);
#pragma unroll
        for (int qr = 0; qr < 2; ++qr) {
            bf16x8 aq[4][2];
#pragma unroll
            for (int fr = 0; fr < 4; ++fr)
#pragma unroll
                for (int kk = 0; kk < 2; ++kk)
                    aq[fr][kk] = *lds_frag(A, wr * 128 + qr * 64 + fr * 16 + l15, kk * 4 + quad);
            __builtin_amdgcn_s_setprio(1);
#pragma unroll
            for (int fr = 0; fr < 4; ++fr)
#pragma unroll
                for (int fc = 0; fc < 4; ++fc)
#pragma unroll
                    for (int kk = 0; kk < 2; ++kk)
                        acc[qr * 4 + fr][fc] = __builtin_amdgcn_mfma_f32_16x16x32_bf16(
                            aq[fr][kk], bq[fc][kk], acc[qr * 4 + fr][fc], 0, 0, 0);
            __builtin_amdgcn_s_setprio(0);
        }

        __builtin_amdgcn_sched_barrier(0);
        __builtin_amdgcn_s_barrier();      // all waves done READING buf[t&1]
        __builtin_amdgcn_sched_barrier(0);
        if (t + 2 < KT) {
            stage(t & 1, (t + 2) * BK);    // overwrite just-consumed buffer
            // outstanding <= 8 (tile t+1) + 8 (tile t+2); wait t+1 only.
            asm volatile("s_waitcnt vmcnt(8)" ::: "memory");
        } else if (t + 1 < KT) {
            asm volatile("s_waitcnt vmcnt(0)" ::: "memory");  // drain last tile
        }
        if (t + 1 < KT) {
            __builtin_amdgcn_sched_barrier(0);
            __builtin_amdgcn_s_barrier();  // buf[(t+1)&1] fully arrived (all waves)
            __builtin_amdgcn_sched_barrier(0);
        }
    }

    // Epilogue. C/D layout (m89/m91-verified): col = lane&15, row = quad*4 + reg.
    // Wave's row for acc[fr8]: wr*128 + (fr8>>2)*64 + (fr8&3)*16 + quad*4 + r.
    float pospart = 0.0f;
#pragma unroll
    for (int fr = 0; fr < 8; ++fr) {
        float rp[4] = {0.f, 0.f, 0.f, 0.f};
#pragma unroll
        for (int fc = 0; fc < 4; ++fc) {
            int c    = wc * 64 + fc * 16 + l15;
            int gcol = col0 + c;
            int cl   = clab[c];
#pragma unroll
            for (int r = 0; r < 4; ++r) {
                int rr   = wr * 128 + (fr >> 2) * 64 + (fr & 3) * 16 + quad * 4 + r;
                int grow = row0 + rr;
                float e  = (grow == gcol) ? 0.0f : __expf(acc[fr][fc][r] * 10.0f);
                rp[r] += e;
                pospart += (rlab[rr] == cl) ? e : 0.0f;
            }
        }
        // row sums: reduce across the 16 columns (lanes sharing a quad)
#pragma unroll
        for (int r = 0; r < 4; ++r) {
            float v = rp[r];
            v += __shfl_xor(v, 1, 64);
            v += __shfl_xor(v, 2, 64);
            v += __shfl_xor(v, 4, 64);
            v += __shfl_xor(v, 8, 64);
            if (l15 == 0)
                atomicAdd(&rowsum[row0 + wr * 128 + (fr >> 2) * 64 + (fr & 3) * 16 + quad * 4 + r], v);
        }
    }
#pragma unroll
    for (int m = 1; m < 64; m <<= 1) pospart += __shfl_xor(pospart, m, 64);
    if (lane == 0) posred[wave] = pospart;
    __syncthreads();
    if (tid == 0) {
        float p = 0.f;
#pragma unroll
        for (int w = 0; w < 8; ++w) p += posred[w];
        atomicAdd(possum, p);
    }
}

__global__ void finalize(const float* __restrict__ rowsum,
                         const float* __restrict__ possum,
                         float* __restrict__ out) {
    const int tid = threadIdx.x;
    float s = 0.f;
    for (int i = tid; i < B_N; i += 256) s += logf(rowsum[i]);
#pragma unroll
    for (int m = 1; m < 64; m <<= 1) s += __shfl_xor(s, m, 64);
    __shared__ float w[4];
    if ((tid & 63) == 0) w[tid >> 6] = s;
    __syncthreads();
    if (tid == 0) {
        float tot = w[0] + w[1] + w[2] + w[3];
        // loss = mean_i log(rowsum_i)  -  log(possum)
        out[0] = tot / (float)B_N - logf(possum[0]);
    }
}

extern "C" void kernel_launch(void* const* d_in, const int* in_sizes, int n_in,
                              void* d_out, int out_size, void* d_ws, size_t ws_size,
                              hipStream_t stream) {
    const float* features = (const float*)d_in[0];
    const int*   targets  = (const int*)d_in[1];
    float*       out      = (float*)d_out;

    // workspace layout: [bf16 fn: 8 MB][rowsum: 4096 f32][possum: 1 f32]
    unsigned short* fnb    = (unsigned short*)d_ws;
    float*          rowsum = (float*)((char*)d_ws + (size_t)B_N * K_D * sizeof(unsigned short));
    float*          possum = rowsum + B_N;

    normalize_bf16<<<B_N, 256, 0, stream>>>(features, fnb, rowsum);
    dim3 grid(B_N / BM, B_N / BM);   // 16 x 16 = 256 blocks = 1 per CU
    gemm_exp_reduce<<<grid, 512, 0, stream>>>(fnb, targets, rowsum, possum);
    finalize<<<1, 256, 0, stream>>>(rowsum, possum, out);
}

// Round 3
// 110.229 us; speedup vs baseline: 1.0160x; 1.0160x over previous
//
#include <hip/hip_runtime.h>
#include <hip/hip_bf16.h>

#define B_N  4096
#define K_D  1024
#define BM   256
#define BK   64
#define KT   (K_D / BK)    // 16 K-tiles
#define HALF (128 * BK)    // shorts per half-tile (128 rows x 64 cols)

typedef __bf16 bf16x8 __attribute__((ext_vector_type(8)));
typedef float  f32x4  __attribute__((ext_vector_type(4)));

// round-to-nearest-even float -> bf16 bits (inputs are finite normals; no NaN path needed)
__device__ __forceinline__ unsigned short f2bf(float x) {
    union { float f; unsigned int u; } v; v.f = x;
    unsigned int r = v.u + 0x7fffu + ((v.u >> 16) & 1u);
    return (unsigned short)(r >> 16);
}

// One block (256 threads) per row: compute L2 norm, write bf16 normalized row.
// Also zeroes rowsum[row] (and possum) so no separate memset node is needed.
__global__ void normalize_bf16(const float* __restrict__ f, unsigned short* __restrict__ fnb,
                               float* __restrict__ rowsum) {
    const int row = blockIdx.x;
    const int tid = threadIdx.x;
    float4 v = ((const float4*)(f + (size_t)row * K_D))[tid];
    float s = v.x * v.x + v.y * v.y + v.z * v.z + v.w * v.w;
#pragma unroll
    for (int m = 1; m < 64; m <<= 1) s += __shfl_xor(s, m, 64);
    __shared__ float wsum[4];
    if ((tid & 63) == 0) wsum[tid >> 6] = s;
    __syncthreads();
    float tot = wsum[0] + wsum[1] + wsum[2] + wsum[3];
    float scale = 1.0f / fmaxf(sqrtf(tot), 1e-12f);
    ushort4 o;
    o.x = f2bf(v.x * scale); o.y = f2bf(v.y * scale);
    o.z = f2bf(v.z * scale); o.w = f2bf(v.w * scale);
    ((ushort4*)(fnb + (size_t)row * K_D))[tid] = o;
    if (tid == 0) rowsum[row] = 0.0f;
    if (row == 0 && tid == 1) rowsum[B_N] = 0.0f;   // possum slot
}

// LDS tile layout: [row][8 slots of 16B], slot XOR-swizzled by (row&7) (T2; measured
// 0 bank conflicts in round 2). Stored via pre-swizzled GLOBAL source (global_load_lds
// writes linearly); read with the same XOR.
__device__ __forceinline__ const bf16x8* lds_frag(const unsigned short* base, int row, int ks) {
    return (const bf16x8*)((const char*)base + row * (BK * 2) + (((ks ^ row) & 7) << 4));
}

// 256x256 tile of sim = fn*fn^T per block (16x16 grid = 1 block/CU, XCD-swizzled).
// 8 waves (2M x 4N); per-wave 128x64 output = 8x4 frags of 16x16x32 bf16 MFMA.
//
// m201-style 8-phase K-loop (T2+T3+T4+T5). Iter i computes K-tiles 2i (buf0, phases
// 1-4) and 2i+1 (buf1, phases 5-8); phase q computes quadrant rows q*32..+32 of the
// wave's A-half. Each phase stages exactly ONE half-tile (2 x global_load_lds/thread).
//
// Region-safety ledger (stage at phase p requires last read of target completed by
// end-barrier of p-1; buf0-B read p1, buf0-A read p1-4, buf1-B read p5, buf1-A p5-8):
//   p1: A[2i+1]h0 -> buf1-A (read through p8 of PREV iter)   p5: A[2i+2]h0 -> buf0-A (read thru p4)
//   p2: A[2i+1]h1 -> buf1-A                                  p6: A[2i+2]h1 -> buf0-A
//   p3: B[2i+2]h0 -> buf0-B (read at p1)                     p7: B[2i+3]h0 -> buf1-B (read at p5)
//   p4: B[2i+2]h1 -> buf0-B + vmcnt(4)                       p8: B[2i+3]h1 -> buf1-B + vmcnt(4)
// vmcnt(4) at p4 forces A[2i+1]+B[2i+1] arrival (first read p5), leaves B[2i+2] flying;
// vmcnt(4) at p8 forces A[2i+2]+B[2i+2] (first read p1 next iter), leaves B[2i+3] flying.
// Last iter (i=7): skip p3-p8 stages; p4 wait becomes vmcnt(0).
__global__ __launch_bounds__(512, 2)
void gemm_exp_reduce(const unsigned short* __restrict__ fnb,
                     const int* __restrict__ labels,
                     float* __restrict__ rowsum,
                     float* __restrict__ possum) {
    __shared__ __align__(16) unsigned short AsB[2][BM * BK]; // 2 x 32 KB
    __shared__ __align__(16) unsigned short BsB[2][BM * BK]; // 2 x 32 KB
    __shared__ int   rlab[BM];
    __shared__ int   clab[BM];
    __shared__ float posred[8];

    // XCD-aware swizzle (T1): 256 blocks, 8 XCDs -> 32 contiguous tiles per XCD.
    const int bid = blockIdx.y * 16 + blockIdx.x;
    const int swz = (bid & 7) * 32 + (bid >> 3);
    const int bi = swz >> 4, bj = swz & 15;

    const int row0 = bi * BM, col0 = bj * BM;
    const int tid  = threadIdx.x;
    const int lane = tid & 63, wave = tid >> 6;
    const int wr = wave >> 2, wc = wave & 3;          // 2M x 4N wave grid
    const int quad = lane >> 4, l15 = lane & 15;

    if (tid < BM) rlab[tid] = labels[row0 + tid];
    else          clab[tid - BM] = labels[col0 + tid - BM];

    const unsigned short* Ag = fnb + (size_t)row0 * K_D;
    const unsigned short* Bg = fnb + (size_t)col0 * K_D;

    f32x4 acc[8][4];
#pragma unroll
    for (int i = 0; i < 8; ++i)
#pragma unroll
        for (int j = 0; j < 4; ++j) {
            f32x4 z = {0.f, 0.f, 0.f, 0.f};
            acc[i][j] = z;
        }

    // Stage one half-tile (128 rows x 64 cols): chunk c = ld*512+tid -> LDS bytes
    // [c*16,+16) (linear, lane-ordered, as global_load_lds requires); global source
    // column pre-swizzled slot^(row&7). r0 is 0 or 128 (multiple of 8 -> row&7 ok).
    auto stage_half = [&](unsigned short* dst, const unsigned short* src, int r0, int k0) {
#pragma unroll
        for (int ld = 0; ld < 2; ++ld) {
            int c  = ld * 512 + tid;
            int r  = c >> 3;
            int gc = ((c ^ r) & 7) << 3;
            __builtin_amdgcn_global_load_lds(
                (const unsigned int*)(src + (size_t)(r0 + r) * K_D + k0 + gc),
                (unsigned int*)(dst + c * 8), 16, 0, 0);
        }
    };

    // Prologue: tile 0 (A+B) + B[1] in flight; wait tile 0 only (last 4 loads = B[1] fly).
    stage_half(AsB[0],        Ag, 0,   0);
    stage_half(AsB[0] + HALF, Ag, 128, 0);
    stage_half(BsB[0],        Bg, 0,   0);
    stage_half(BsB[0] + HALF, Bg, 128, 0);
    stage_half(BsB[1],        Bg, 0,   BK);
    stage_half(BsB[1] + HALF, Bg, 128, BK);
    asm volatile("s_waitcnt vmcnt(4)" ::: "memory");
    __builtin_amdgcn_sched_barrier(0);
    __builtin_amdgcn_s_barrier();

    for (int i = 0; i < KT / 2; ++i) {
        const bool more = (i < KT / 2 - 1);
#pragma unroll
        for (int h = 0; h < 2; ++h) {                 // h=0: tile 2i (buf0), h=1: tile 2i+1 (buf1)
            const unsigned short* At = AsB[h];
            const unsigned short* Bt = BsB[h];
            bf16x8 bq[4][2];
#pragma unroll
            for (int q = 0; q < 4; ++q) {             // phase = h*4 + q + 1
                // --- ds-load register subtiles for this phase ---
                bf16x8 af[2][2];
#pragma unroll
                for (int fr = 0; fr < 2; ++fr)
#pragma unroll
                    for (int kk = 0; kk < 2; ++kk)
                        af[fr][kk] = *lds_frag(At, wr * 128 + q * 32 + fr * 16 + l15,
                                               kk * 4 + quad);
                if (q == 0) {                          // B frags once per K-tile (held 4 phases)
#pragma unroll
                    for (int fc = 0; fc < 4; ++fc)
#pragma unroll
                        for (int kk = 0; kk < 2; ++kk)
                            bq[fc][kk] = *lds_frag(Bt, wc * 64 + fc * 16 + l15,
                                                   kk * 4 + quad);
                }
                // --- stage exactly one half-tile (see ledger above) ---
                if (h == 0) {
                    if (q == 0) stage_half(AsB[1],        Ag, 0,   (2 * i + 1) * BK);
                    if (q == 1) stage_half(AsB[1] + HALF, Ag, 128, (2 * i + 1) * BK);
                    if (q == 2 && more) stage_half(BsB[0], Bg, 0,  (2 * i + 2) * BK);
                    if (q == 3) {
                        if (more) {
                            stage_half(BsB[0] + HALF, Bg, 128, (2 * i + 2) * BK);
                            asm volatile("s_waitcnt vmcnt(4)" ::: "memory");
                        } else {
                            asm volatile("s_waitcnt vmcnt(0)" ::: "memory");
                        }
                    }
                } else if (more) {
                    if (q == 0) stage_half(AsB[0],        Ag, 0,   (2 * i + 2) * BK);
                    if (q == 1) stage_half(AsB[0] + HALF, Ag, 128, (2 * i + 2) * BK);
                    if (q == 2) stage_half(BsB[1],        Bg, 0,   (2 * i + 3) * BK);
                    if (q == 3) {
                        stage_half(BsB[1] + HALF, Bg, 128, (2 * i + 3) * BK);
                        asm volatile("s_waitcnt vmcnt(4)" ::: "memory");
                    }
                }
                // --- barrier; drain own ds_reads; MFMA cluster under setprio ---
                __builtin_amdgcn_sched_barrier(0);
                __builtin_amdgcn_s_barrier();
                asm volatile("s_waitcnt lgkmcnt(0)" ::: "memory");
                __builtin_amdgcn_sched_barrier(0);
                __builtin_amdgcn_s_setprio(1);
#pragma unroll
                for (int fr = 0; fr < 2; ++fr)
#pragma unroll
                    for (int fc = 0; fc < 4; ++fc)
#pragma unroll
                        for (int kk = 0; kk < 2; ++kk)
                            acc[q * 2 + fr][fc] = __builtin_amdgcn_mfma_f32_16x16x32_bf16(
                                af[fr][kk], bq[fc][kk], acc[q * 2 + fr][fc], 0, 0, 0);
                __builtin_amdgcn_s_setprio(0);
                __builtin_amdgcn_sched_barrier(0);
                __builtin_amdgcn_s_barrier();
            }
        }
    }

    // Epilogue. C/D layout (m89/m91): col = lane&15, row = quad*4 + reg.
    // acc[q*2+fr] covers rows wr*128 + q*32 + fr*16 (+quad*4+r).
    float pospart = 0.0f;
#pragma unroll
    for (int fr = 0; fr < 8; ++fr) {
        const int rbase = wr * 128 + (fr >> 1) * 32 + (fr & 1) * 16 + quad * 4;
        float rp[4] = {0.f, 0.f, 0.f, 0.f};
#pragma unroll
        for (int fc = 0; fc < 4; ++fc) {
            int c    = wc * 64 + fc * 16 + l15;
            int gcol = col0 + c;
            int cl   = clab[c];
#pragma unroll
            for (int r = 0; r < 4; ++r) {
                int grow = row0 + rbase + r;
                float e  = (grow == gcol) ? 0.0f : __expf(acc[fr][fc][r] * 10.0f);
                rp[r] += e;
                pospart += (rlab[rbase + r] == cl) ? e : 0.0f;
            }
        }
        // row sums: reduce across the 16 columns (lanes sharing a quad)
#pragma unroll
        for (int r = 0; r < 4; ++r) {
            float v = rp[r];
            v += __shfl_xor(v, 1, 64);
            v += __shfl_xor(v, 2, 64);
            v += __shfl_xor(v, 4, 64);
            v += __shfl_xor(v, 8, 64);
            if (l15 == 0)
                atomicAdd(&rowsum[row0 + rbase + r], v);
        }
    }
#pragma unroll
    for (int m = 1; m < 64; m <<= 1) pospart += __shfl_xor(pospart, m, 64);
    if (lane == 0) posred[wave] = pospart;
    __syncthreads();
    if (tid == 0) {
        float p = 0.f;
#pragma unroll
        for (int w = 0; w < 8; ++w) p += posred[w];
        atomicAdd(possum, p);
    }
}

__global__ void finalize(const float* __restrict__ rowsum,
                         const float* __restrict__ possum,
                         float* __restrict__ out) {
    const int tid = threadIdx.x;
    float s = 0.f;
    for (int i = tid; i < B_N; i += 256) s += logf(rowsum[i]);
#pragma unroll
    for (int m = 1; m < 64; m <<= 1) s += __shfl_xor(s, m, 64);
    __shared__ float w[4];
    if ((tid & 63) == 0) w[tid >> 6] = s;
    __syncthreads();
    if (tid == 0) {
        float tot = w[0] + w[1] + w[2] + w[3];
        // loss = mean_i log(rowsum_i)  -  log(possum)
        out[0] = tot / (float)B_N - logf(possum[0]);
    }
}

extern "C" void kernel_launch(void* const* d_in, const int* in_sizes, int n_in,
                              void* d_out, int out_size, void* d_ws, size_t ws_size,
                              hipStream_t stream) {
    const float* features = (const float*)d_in[0];
    const int*   targets  = (const int*)d_in[1];
    float*       out      = (float*)d_out;

    // workspace layout: [bf16 fn: 8 MB][rowsum: 4096 f32][possum: 1 f32]
    unsigned short* fnb    = (unsigned short*)d_ws;
    float*          rowsum = (float*)((char*)d_ws + (size_t)B_N * K_D * sizeof(unsigned short));
    float*          possum = rowsum + B_N;

    normalize_bf16<<<B_N, 256, 0, stream>>>(features, fnb, rowsum);
    dim3 grid(B_N / BM, B_N / BM);   // 16 x 16 = 256 blocks = 1 per CU
    gemm_exp_reduce<<<grid, 512, 0, stream>>>(fnb, targets, rowsum, possum);
    finalize<<<1, 256, 0, stream>>>(rowsum, possum, out);
}